// Round 1
// baseline (151.841 us; speedup 1.0000x reference)
//
#include <hip/hip_runtime.h>

#define P_IDS 512
#define DIM 8
#define QMIN 0.01f
#define REP 10.0f

// Phase A: q_i = arctanh(beta_i)^2 + QMIN; per-particle argmax via 64-bit atomicMax.
// Key = (float_bits(q) << 32) | ~i : positive-float bits are order-preserving, and
// ~i gives min-index on exact q ties (matches reference's first-argmax semantics).
__global__ void q_kernel(const float* __restrict__ beta,
                         const int* __restrict__ pid,
                         float* __restrict__ q_out,
                         unsigned long long* __restrict__ keys,
                         int n) {
    int i = blockIdx.x * blockDim.x + threadIdx.x;
    if (i >= n) return;
    float b = beta[i];
    float at = 0.5f * logf((1.0f + b) / (1.0f - b));   // arctanh
    float q = fmaf(at, at, QMIN);
    q_out[i] = q;
    unsigned long long key =
        ((unsigned long long)__float_as_uint(q) << 32) |
        (unsigned long long)(unsigned int)(~(unsigned int)i);
    atomicMax(&keys[pid[i]], key);
}

// Phase B: decode keys -> q_alpha (sanitized: 0 for noise pid 0 / empty segments),
// gather x_alpha. One block of 512 threads.
__global__ void decode_kernel(const unsigned long long* __restrict__ keys,
                              const float* __restrict__ x,
                              float* __restrict__ q_alpha,
                              float* __restrict__ x_alpha) {
    int p = threadIdx.x;
    unsigned long long key = keys[p];
    bool valid = (key != 0ULL) && (p != 0);   // q>=0.01 -> key!=0 for any occupied segment
    float qa = valid ? __uint_as_float((unsigned int)(key >> 32)) : 0.0f;
    int idx = valid ? (int)(~(unsigned int)(key & 0xFFFFFFFFull)) : 0;
    q_alpha[p] = qa;
#pragma unroll
    for (int d = 0; d < DIM; ++d) x_alpha[p * DIM + d] = x[idx * DIM + d];
}

// Phase C: dense N x P sweep. x_alpha/q_alpha staged in LDS; p-loop is wave-uniform
// so LDS reads broadcast (no bank conflicts). Per-thread accumulate, wave shuffle
// reduce, block reduce, one atomicAdd per block.
__launch_bounds__(256)
__global__ void loss_kernel(const float* __restrict__ x,
                            const float* __restrict__ q,
                            const int* __restrict__ pid,
                            const float* __restrict__ q_alpha,
                            const float* __restrict__ x_alpha,
                            float* __restrict__ out,
                            int n) {
    __shared__ float s_xa[P_IDS * DIM];   // 16 KB
    __shared__ float s_qa[P_IDS];         // 2 KB
    for (int t = threadIdx.x; t < P_IDS * DIM; t += 256) s_xa[t] = x_alpha[t];
    for (int t = threadIdx.x; t < P_IDS; t += 256) s_qa[t] = q_alpha[t];
    __syncthreads();

    int i = blockIdx.x * 256 + threadIdx.x;
    float partial = 0.0f;
    if (i < n) {
        const float4* x4 = (const float4*)x;
        float4 a = x4[i * 2];
        float4 c = x4[i * 2 + 1];
        float xi[DIM] = {a.x, a.y, a.z, a.w, c.x, c.y, c.z, c.w};
        float qi = q[i];
        int myp = pid[i];
        float acc = 0.0f;
        for (int p = 0; p < P_IDS; ++p) {
            float qa = s_qa[p];
            float sq = 0.0f;
#pragma unroll
            for (int d = 0; d < DIM; ++d) {
                float dl = xi[d] - s_xa[p * DIM + d];
                sq = fmaf(dl, dl, sq);
            }
            float vr = fmaxf(1.0f - sqrtf(sq), 0.0f);
            float term = (p == myp) ? (sq * qa) : (REP * vr * qa);
            acc += term;
        }
        partial = qi * acc;
    }

    // wave (64-lane) shuffle reduction
#pragma unroll
    for (int off = 32; off > 0; off >>= 1)
        partial += __shfl_down(partial, off, 64);

    __shared__ float s_red[4];
    if ((threadIdx.x & 63) == 0) s_red[threadIdx.x >> 6] = partial;
    __syncthreads();
    if (threadIdx.x == 0) {
        float s = (s_red[0] + s_red[1] + s_red[2] + s_red[3]) / (float)n;
        atomicAdd(out, s);
    }
}

extern "C" void kernel_launch(void* const* d_in, const int* in_sizes, int n_in,
                              void* d_out, int out_size, void* d_ws, size_t ws_size,
                              hipStream_t stream) {
    int n = in_sizes[0];                              // N hits
    const float* beta = (const float*)d_in[1];
    const float* x    = (const float*)d_in[2];
    const int*   pid  = (const int*)d_in[4];
    float* out = (float*)d_out;

    // workspace layout
    char* ws = (char*)d_ws;
    unsigned long long* keys = (unsigned long long*)ws;           // 4096 B
    float* q       = (float*)(ws + 4096);                         // 4*n B
    float* q_alpha = (float*)(ws + 4096 + 4 * (size_t)n);         // 2048 B
    float* x_alpha = (float*)(ws + 4096 + 4 * (size_t)n + 2048);  // 16384 B

    hipMemsetAsync(keys, 0, P_IDS * sizeof(unsigned long long), stream);
    hipMemsetAsync(out, 0, out_size * sizeof(float), stream);

    int blocks = (n + 255) / 256;
    q_kernel<<<blocks, 256, 0, stream>>>(beta, pid, q, keys, n);
    decode_kernel<<<1, P_IDS, 0, stream>>>(keys, x, q_alpha, x_alpha);
    loss_kernel<<<blocks, 256, 0, stream>>>(x, q, pid, q_alpha, x_alpha, out, n);
}

// Round 2
// 101.840 us; speedup vs baseline: 1.4910x; 1.4910x over previous
//
#include <hip/hip_runtime.h>

#define P_IDS 512
#define DIM 8
#define QMIN 0.01f
#define REP 10.0f
#define A_BLOCKS 128      // stage-A blocks == number of partial key tables
#define CHUNK 128         // particles per loss-kernel chunk (P_IDS / 4)

typedef unsigned long long ull;

// Stage A: q_i = arctanh(beta_i)^2 + QMIN; per-block segmented argmax into a
// private LDS table (key = qbits<<32 | ~i : order-preserving for q>0, min-index
// on ties), flushed non-atomically to tables[block][512]. No global atomics.
__launch_bounds__(256)
__global__ void stageA_kernel(const float* __restrict__ beta,
                              const int* __restrict__ pid,
                              float* __restrict__ q_out,
                              ull* __restrict__ tables,
                              int n) {
    __shared__ ull s_keys[P_IDS];
    for (int t = threadIdx.x; t < P_IDS; t += 256) s_keys[t] = 0ULL;
    __syncthreads();
    for (int i = blockIdx.x * 256 + threadIdx.x; i < n; i += gridDim.x * 256) {
        float b = beta[i];
        float at = 0.5f * logf((1.0f + b) / (1.0f - b));   // arctanh
        float q = fmaf(at, at, QMIN);
        q_out[i] = q;
        ull key = ((ull)__float_as_uint(q) << 32) |
                  (ull)(unsigned int)(~(unsigned int)i);
        atomicMax(&s_keys[pid[i]], key);
    }
    __syncthreads();
    for (int t = threadIdx.x; t < P_IDS; t += 256)
        tables[blockIdx.x * P_IDS + t] = s_keys[t];
}

// Stage B: reduce the A_BLOCKS partial tables, decode -> meta[p] = (q_alpha,
// ||x_alpha||^2), gather x_alpha. Also zeroes the output accumulator.
// Grid: 8 blocks x 64 threads (one thread per particle id).
__launch_bounds__(64)
__global__ void stageB_kernel(const ull* __restrict__ tables,
                              const float* __restrict__ x,
                              float2* __restrict__ meta,
                              float* __restrict__ x_alpha,
                              float* __restrict__ out) {
    int p = blockIdx.x * 64 + threadIdx.x;
    ull k = 0ULL;
    for (int t = 0; t < A_BLOCKS; ++t) {
        ull v = tables[t * P_IDS + p];          // consecutive p -> coalesced
        k = (v > k) ? v : k;
    }
    bool valid = (k != 0ULL) && (p != 0);       // q >= 0.01 -> occupied keys != 0
    float qa = valid ? __uint_as_float((unsigned int)(k >> 32)) : 0.0f;
    int idx = valid ? (int)(~(unsigned int)(k & 0xFFFFFFFFull)) : 0;
    float xa2 = 0.0f;
#pragma unroll
    for (int d = 0; d < DIM; ++d) {
        float v = x[idx * DIM + d];
        x_alpha[p * DIM + d] = v;
        xa2 = fmaf(v, v, xa2);
    }
    meta[p] = make_float2(qa, xa2);
    if (p == 0) out[0] = 0.0f;                  // replaces hipMemsetAsync(out)
}

// Loss: each block = 256 hits x one 128-particle chunk (grid = hit_blocks*4).
// sq via dot form: ||xi||^2 - 2 xi.xa + ||xa||^2 (8 FMA vs 16 sub+fma).
__launch_bounds__(256)
__global__ void loss_kernel(const float* __restrict__ x,
                            const float* __restrict__ q,
                            const int* __restrict__ pid,
                            const float2* __restrict__ meta,
                            const float* __restrict__ x_alpha,
                            float* __restrict__ out,
                            int n) {
    __shared__ float  s_xa[CHUNK * DIM];   // 4 KB
    __shared__ float2 s_meta[CHUNK];       // 1 KB
    int chunk = blockIdx.x & 3;
    int hb    = blockIdx.x >> 2;
    int p0    = chunk * CHUNK;

    // stage chunk's x_alpha (1024 floats) + meta (128 float2)
    if (threadIdx.x < CHUNK * DIM / 4)
        ((float4*)s_xa)[threadIdx.x] =
            ((const float4*)(x_alpha + p0 * DIM))[threadIdx.x];
    if (threadIdx.x < CHUNK) s_meta[threadIdx.x] = meta[p0 + threadIdx.x];
    __syncthreads();

    int i = hb * 256 + threadIdx.x;
    float partial = 0.0f;
    if (i < n) {
        const float4* x4 = (const float4*)x;
        float4 a = x4[i * 2];
        float4 c = x4[i * 2 + 1];
        float xi[DIM] = {a.x, a.y, a.z, a.w, c.x, c.y, c.z, c.w};
        float xi2 = 0.0f;
#pragma unroll
        for (int d = 0; d < DIM; ++d) xi2 = fmaf(xi[d], xi[d], xi2);
        float qi = q[i];
        int myj = pid[i] - p0;                 // in [0,CHUNK) iff own pid in chunk
        float acc = 0.0f;
#pragma unroll 4
        for (int j = 0; j < CHUNK; ++j) {
            float2 m = s_meta[j];
            const float* xa = &s_xa[j * DIM];
            float dot = 0.0f;
#pragma unroll
            for (int d = 0; d < DIM; ++d) dot = fmaf(xi[d], xa[d], dot);
            float sq = fmaxf(fmaf(-2.0f, dot, xi2 + m.y), 0.0f);
            float dist = __builtin_amdgcn_sqrtf(sq);
            float vr = fmaxf(1.0f - dist, 0.0f);
            float t = (j == myj) ? sq : REP * vr;
            acc = fmaf(t, m.x, acc);
        }
        partial = qi * acc;
    }

    // wave (64-lane) shuffle reduction, then cross-wave via LDS
#pragma unroll
    for (int off = 32; off > 0; off >>= 1)
        partial += __shfl_down(partial, off, 64);
    __shared__ float s_red[4];
    if ((threadIdx.x & 63) == 0) s_red[threadIdx.x >> 6] = partial;
    __syncthreads();
    if (threadIdx.x == 0) {
        float s = (s_red[0] + s_red[1] + s_red[2] + s_red[3]) / (float)n;
        atomicAdd(out, s);
    }
}

extern "C" void kernel_launch(void* const* d_in, const int* in_sizes, int n_in,
                              void* d_out, int out_size, void* d_ws, size_t ws_size,
                              hipStream_t stream) {
    int n = in_sizes[0];
    const float* beta = (const float*)d_in[1];
    const float* x    = (const float*)d_in[2];
    const int*   pid  = (const int*)d_in[4];
    float* out = (float*)d_out;

    // workspace layout (16B-aligned segments)
    char* ws = (char*)d_ws;
    size_t tab_bytes = (size_t)A_BLOCKS * P_IDS * sizeof(ull);        // 512 KB
    size_t q_bytes   = (((size_t)n * 4) + 255) & ~(size_t)255;
    ull*    tables  = (ull*)ws;
    float*  q       = (float*)(ws + tab_bytes);
    float2* meta    = (float2*)(ws + tab_bytes + q_bytes);
    float*  x_alpha = (float*)(ws + tab_bytes + q_bytes + P_IDS * sizeof(float2));

    stageA_kernel<<<A_BLOCKS, 256, 0, stream>>>(beta, pid, q, tables, n);
    stageB_kernel<<<P_IDS / 64, 64, 0, stream>>>(tables, x, meta, x_alpha, out);
    int hit_blocks = (n + 255) / 256;
    loss_kernel<<<hit_blocks * 4, 256, 0, stream>>>(x, q, pid, meta, x_alpha, out, n);
}

// Round 3
// 96.584 us; speedup vs baseline: 1.5721x; 1.0544x over previous
//
#include <hip/hip_runtime.h>

#define P_IDS 512
#define DIM 8
#define QMIN 0.01f
#define REP 10.0f
#define CHUNK 64               // particles per loss-block chunk
#define NCHUNK (P_IDS / CHUNK) // 8
#define HPT 4                  // hits per thread (register-blocked)
#define HB (256 * HPT)         // 1024 hits per block

typedef unsigned long long ull;

// Stage A: q_i = arctanh(beta_i)^2 + QMIN; per-block segmented argmax into LDS
// (key = qbits<<32 | ~i -> order-preserving for q>0, min-index on ties).
// One hit per thread, 392 blocks: no grid-stride, good launch parallelism.
__launch_bounds__(256)
__global__ void stageA_kernel(const float* __restrict__ beta,
                              const int* __restrict__ pid,
                              float* __restrict__ q_out,
                              ull* __restrict__ tables,
                              int n) {
    __shared__ ull s_keys[P_IDS];
    s_keys[threadIdx.x] = 0ULL;
    s_keys[threadIdx.x + 256] = 0ULL;
    __syncthreads();
    int i = blockIdx.x * 256 + threadIdx.x;
    if (i < n) {
        float b = beta[i];
        float at = 0.5f * logf((1.0f + b) / (1.0f - b));   // arctanh
        float qv = fmaf(at, at, QMIN);
        q_out[i] = qv;
        ull key = ((ull)__float_as_uint(qv) << 32) |
                  (ull)(unsigned int)(~(unsigned int)i);
        atomicMax(&s_keys[pid[i]], key);
    }
    __syncthreads();
    ull* dst = tables + (size_t)blockIdx.x * P_IDS;
    dst[threadIdx.x] = s_keys[threadIdx.x];
    dst[threadIdx.x + 256] = s_keys[threadIdx.x + 256];
}

// Stage B: one block per particle id; 64 threads reduce the ntab partial keys,
// shuffle-max, lane 0 decodes + gathers x_alpha + precomputes ||x_alpha||^2.
// Block 0 also zeroes the output accumulator (replaces memset).
__launch_bounds__(64)
__global__ void stageB_kernel(const ull* __restrict__ tables, int ntab,
                              const float* __restrict__ x,
                              float2* __restrict__ meta,
                              float* __restrict__ x_alpha,
                              float* __restrict__ out) {
    int p = blockIdx.x;
    ull k = 0ULL;
    for (int t = threadIdx.x; t < ntab; t += 64) {
        ull v = tables[(size_t)t * P_IDS + p];
        k = (v > k) ? v : k;
    }
#pragma unroll
    for (int off = 32; off > 0; off >>= 1) {
        ull o = __shfl_down(k, off, 64);
        k = (o > k) ? o : k;
    }
    if (threadIdx.x == 0) {
        bool valid = (k != 0ULL) && (p != 0);
        float qa = valid ? __uint_as_float((unsigned int)(k >> 32)) : 0.0f;
        int idx = valid ? (int)(~(unsigned int)(k & 0xFFFFFFFFull)) : 0;
        float4 a = ((const float4*)x)[idx * 2];
        float4 b = ((const float4*)x)[idx * 2 + 1];
        float xa2 = a.x * a.x;
        xa2 = fmaf(a.y, a.y, xa2); xa2 = fmaf(a.z, a.z, xa2); xa2 = fmaf(a.w, a.w, xa2);
        xa2 = fmaf(b.x, b.x, xa2); xa2 = fmaf(b.y, b.y, xa2); xa2 = fmaf(b.z, b.z, xa2);
        xa2 = fmaf(b.w, b.w, xa2);
        ((float4*)x_alpha)[p * 2] = a;
        ((float4*)x_alpha)[p * 2 + 1] = b;
        meta[p] = make_float2(qa, xa2);
        if (p == 0) out[0] = 0.0f;
    }
}

// Loss: block = 1024 hits (4 per thread, register-blocked) x 64-particle chunk.
// Dense loop: repulsive term only; sqrt path skipped when no lane has sq < 1
// (P ~ 5% per wave-iter). Own-pair attractive correction applied post-loop in
// the one chunk-block containing the hit's pid. x10 and /N deferred to the end.
__launch_bounds__(256)
__global__ void loss_kernel(const float* __restrict__ x,
                            const float* __restrict__ q,
                            const int* __restrict__ pid,
                            const float2* __restrict__ meta,
                            const float* __restrict__ x_alpha,
                            float* __restrict__ out,
                            int n) {
    __shared__ float  s_xa[CHUNK * DIM];   // 2 KB
    __shared__ float2 s_meta[CHUNK];       // 512 B
    int chunk = blockIdx.x & (NCHUNK - 1);
    int hb    = blockIdx.x / NCHUNK;
    int p0    = chunk * CHUNK;
    if (threadIdx.x < CHUNK * DIM / 4)
        ((float4*)s_xa)[threadIdx.x] =
            ((const float4*)(x_alpha + p0 * DIM))[threadIdx.x];
    if (threadIdx.x < CHUNK) s_meta[threadIdx.x] = meta[p0 + threadIdx.x];
    __syncthreads();

    float xi[HPT][DIM], xi2[HPT], qi[HPT], acc[HPT];
    int   myj[HPT];
    int base = hb * HB + threadIdx.x;
#pragma unroll
    for (int h = 0; h < HPT; ++h) {
        int i = base + h * 256;
        bool act = i < n;
        int ii = act ? i : 0;
        float4 v0 = ((const float4*)x)[ii * 2];
        float4 v1 = ((const float4*)x)[ii * 2 + 1];
        xi[h][0] = v0.x; xi[h][1] = v0.y; xi[h][2] = v0.z; xi[h][3] = v0.w;
        xi[h][4] = v1.x; xi[h][5] = v1.y; xi[h][6] = v1.z; xi[h][7] = v1.w;
        float s = 0.0f;
#pragma unroll
        for (int d = 0; d < DIM; ++d) s = fmaf(xi[h][d], xi[h][d], s);
        xi2[h] = s;
        qi[h]  = act ? q[ii] : 0.0f;       // qi=0 masks inactive lanes' acc
        myj[h] = act ? (pid[ii] - p0) : -1;
        acc[h] = 0.0f;
    }

    for (int j = 0; j < CHUNK; ++j) {
        float2 m  = s_meta[j];
        float4 a0 = ((const float4*)s_xa)[j * 2];
        float4 a1 = ((const float4*)s_xa)[j * 2 + 1];
        float sq[HPT];
#pragma unroll
        for (int h = 0; h < HPT; ++h) {
            float dot = xi[h][0] * a0.x;
            dot = fmaf(xi[h][1], a0.y, dot); dot = fmaf(xi[h][2], a0.z, dot);
            dot = fmaf(xi[h][3], a0.w, dot); dot = fmaf(xi[h][4], a1.x, dot);
            dot = fmaf(xi[h][5], a1.y, dot); dot = fmaf(xi[h][6], a1.z, dot);
            dot = fmaf(xi[h][7], a1.w, dot);
            sq[h] = fmaxf(fmaf(-2.0f, dot, xi2[h] + m.y), 0.0f);
        }
        float mn = fminf(fminf(sq[0], sq[1]), fminf(sq[2], sq[3]));
        if (__any(mn < 1.0f)) {            // vr == 0 for every pair otherwise
#pragma unroll
            for (int h = 0; h < HPT; ++h) {
                float vr = fmaxf(1.0f - __builtin_amdgcn_sqrtf(sq[h]), 0.0f);
                acc[h] = fmaf(vr, m.x, acc[h]);
            }
        }
    }

    float partial = 0.0f;
#pragma unroll
    for (int h = 0; h < HPT; ++h) {
        float t = REP * acc[h];            // repulsive, pre-scaled
        int j = myj[h];
        if (j >= 0 && j < CHUNK) {         // own-pair correction lives here
            float2 m = s_meta[j];
            float dot = xi[h][0] * s_xa[j * DIM + 0];
#pragma unroll
            for (int d = 1; d < DIM; ++d) dot = fmaf(xi[h][d], s_xa[j * DIM + d], dot);
            float sq = fmaxf(fmaf(-2.0f, dot, xi2[h] + m.y), 0.0f);
            float vr = fmaxf(1.0f - __builtin_amdgcn_sqrtf(sq), 0.0f);
            t += m.x * (sq - REP * vr);    // replace repulsive with attractive
        }
        partial = fmaf(qi[h], t, partial);
    }

#pragma unroll
    for (int off = 32; off > 0; off >>= 1)
        partial += __shfl_down(partial, off, 64);
    __shared__ float s_red[4];
    if ((threadIdx.x & 63) == 0) s_red[threadIdx.x >> 6] = partial;
    __syncthreads();
    if (threadIdx.x == 0)
        atomicAdd(out, (s_red[0] + s_red[1] + s_red[2] + s_red[3]) / (float)n);
}

extern "C" void kernel_launch(void* const* d_in, const int* in_sizes, int n_in,
                              void* d_out, int out_size, void* d_ws, size_t ws_size,
                              hipStream_t stream) {
    int n = in_sizes[0];
    const float* beta = (const float*)d_in[1];
    const float* x    = (const float*)d_in[2];
    const int*   pid  = (const int*)d_in[4];
    float* out = (float*)d_out;

    int a_blocks = (n + 255) / 256;                               // 392
    char* ws = (char*)d_ws;
    size_t tab_bytes = (size_t)a_blocks * P_IDS * sizeof(ull);    // ~1.6 MB
    tab_bytes = (tab_bytes + 255) & ~(size_t)255;
    size_t q_bytes = (((size_t)n * 4) + 255) & ~(size_t)255;
    ull*    tables  = (ull*)ws;
    float*  q       = (float*)(ws + tab_bytes);
    float2* meta    = (float2*)(ws + tab_bytes + q_bytes);
    float*  x_alpha = (float*)(ws + tab_bytes + q_bytes + P_IDS * sizeof(float2));

    stageA_kernel<<<a_blocks, 256, 0, stream>>>(beta, pid, q, tables, n);
    stageB_kernel<<<P_IDS, 64, 0, stream>>>(tables, a_blocks, x, meta, x_alpha, out);
    int hit_blocks = (n + HB - 1) / HB;                           // 98
    loss_kernel<<<hit_blocks * NCHUNK, 256, 0, stream>>>(x, q, pid, meta, x_alpha, out, n);
}